// Round 1
// baseline (404.829 us; speedup 1.0000x reference)
//
#include <hip/hip_runtime.h>
#include <hip/hip_bf16.h>
#include <stdint.h>
#include <stddef.h>

#define D_M   1024
#define N_H   16
#define D_K   64
#define S_LEN 2048
#define N_B   4
#define P_LEN 1792
#define M_ROWS (N_B*S_LEN)   // 8192

typedef unsigned short u16;
typedef __bf16  bf16x8 __attribute__((ext_vector_type(8)));
typedef float   f32x4  __attribute__((ext_vector_type(4)));

#define MFMA16(a,b,c) __builtin_amdgcn_mfma_f32_16x16x32_bf16((a),(b),(c),0,0,0)

#define GLDS16(gp, lp) __builtin_amdgcn_global_load_lds( \
    (__attribute__((address_space(1))) void*)(gp), \
    (__attribute__((address_space(3))) void*)(lp), 16, 0, 0)

__device__ __forceinline__ u16 f2bf(float f){
  unsigned u = __builtin_bit_cast(unsigned, f);
  u += 0x7FFFu + ((u>>16)&1u);     // RNE round to bf16
  return (u16)(u>>16);
}

// ---------------- fp32 -> bf16 convert (vectorized, 8 elems/thread/iter) ----
__global__ void cvt_bf16(const float* __restrict__ in, u16* __restrict__ out, int n8){
  typedef u16 u16x8 __attribute__((ext_vector_type(8)));
  for (int i = blockIdx.x*blockDim.x + threadIdx.x; i < n8; i += gridDim.x*blockDim.x){
    const float4* p = (const float4*)(in + (size_t)i*8);
    float4 a = p[0], b = p[1];
    u16x8 o;
    o[0]=f2bf(a.x); o[1]=f2bf(a.y); o[2]=f2bf(a.z); o[3]=f2bf(a.w);
    o[4]=f2bf(b.x); o[5]=f2bf(b.y); o[6]=f2bf(b.z); o[7]=f2bf(b.w);
    *(u16x8*)(out + (size_t)i*8) = o;
  }
}

// ---------------- 128x128 bf16 NT GEMM (C = A * B^T + bias), m97 structure --
// A: (M,K) row-major bf16.  Bm: (N,K) row-major bf16 (i.e. B transposed).
// MODE 0: out bf16 (B,H,S,dk) head-split       (Q / K projections)
// MODE 1: out bf16 (B,H,dk,S) head-split, transposed   (V projection)
// MODE 2: out fp32 (M,N) row-major             (output projection -> d_out)
template<int MODE>
__global__ __launch_bounds__(256,2)
void gemm_bt(const u16* __restrict__ A, const u16* __restrict__ Bm,
             const float* __restrict__ bias, void* __restrict__ Cout)
{
  constexpr int Kd = 1024, N = 1024;
  __shared__ __align__(16) u16 As[128*32];
  __shared__ __align__(16) u16 Bs[128*32];
  const int tid  = threadIdx.x;
  const int wid  = tid >> 6, lane = tid & 63;
  const int rowBase = blockIdx.x * 128, colBase = blockIdx.y * 128;

  // staging: wave w covers 1KB chunks; lane lane -> row w*16+lane/4, col (lane&3)*8
  const int srow = (wid<<4) + (lane>>2);
  const int scol = (lane&3) << 3;
  const u16* Ag0 = A  + (size_t)(rowBase + srow)*Kd + scol;
  const u16* Ag1 = Ag0 + (size_t)64*Kd;
  const u16* Bg0 = Bm + (size_t)(colBase + srow)*Kd + scol;
  const u16* Bg1 = Bg0 + (size_t)64*Kd;
  u16* AsW0 = As + (wid<<9);          // wid*512 elems = 1KB per wave
  u16* AsW1 = As + 2048 + (wid<<9);
  u16* BsW0 = Bs + (wid<<9);
  u16* BsW1 = Bs + 2048 + (wid<<9);

  f32x4 acc[4][4] = {};
  const int fr = lane & 15, fk = (lane>>4) << 3;
  const int wr = (wid>>1) << 6, wc = (wid&1) << 6;   // wave's 64x64 sub-tile

  for (int kt = 0; kt < Kd/32; ++kt){
    __syncthreads();                      // previous compute done before overwrite
    const int ko = kt*32;
    GLDS16(Ag0+ko, AsW0); GLDS16(Ag1+ko, AsW1);
    GLDS16(Bg0+ko, BsW0); GLDS16(Bg1+ko, BsW1);
    __syncthreads();                      // drains vmcnt before barrier (compiler)
    bf16x8 af[4], bf[4];
#pragma unroll
    for (int i=0;i<4;++i) af[i] = *(const bf16x8*)&As[(wr + i*16 + fr)*32 + fk];
#pragma unroll
    for (int i=0;i<4;++i) bf[i] = *(const bf16x8*)&Bs[(wc + i*16 + fr)*32 + fk];
#pragma unroll
    for (int i=0;i<4;++i)
#pragma unroll
      for (int j=0;j<4;++j)
        acc[i][j] = MFMA16(af[i], bf[j], acc[i][j]);
  }

  // epilogue: C row = (lane>>4)*4+reg, col = lane&15 within each 16x16 frag
  const int rr0 = (lane>>4) << 2;
#pragma unroll
  for (int i=0;i<4;++i){
#pragma unroll
    for (int j=0;j<4;++j){
      const int gc = colBase + wc + j*16 + fr;
      const float bb = bias[gc];
#pragma unroll
      for (int r=0;r<4;++r){
        const int gr = rowBase + wr + i*16 + rr0 + r;
        const float v = acc[i][j][r] + bb;
        if (MODE == 2){
          ((float*)Cout)[(size_t)gr*N + gc] = v;
        } else {
          const int b = gr >> 11, s = gr & 2047;     // S_LEN = 2048
          const int h = gc >> 6,  k = gc & 63;       // D_K = 64
          if (MODE == 0)
            ((u16*)Cout)[(((size_t)(b*N_H + h))*S_LEN + s)*D_K + k] = f2bf(v);
          else
            ((u16*)Cout)[(((size_t)(b*N_H + h))*D_K + k)*S_LEN + s] = f2bf(v);
        }
      }
    }
  }
}

// ---------------- flash attention tile step (one wave, 16 q-rows x 32 keys) --
// MM = 0: no mask (candidate vs prefix keys)
// MM = 1: causal  (key_idx > q_idx masked)
// MM = 2: self-diagonal only (candidate self key), with clamped loads
template<int MM>
__device__ __forceinline__ void attn_tile(
  const u16* __restrict__ Kbase, const u16* __restrict__ Vbase,
  u16* __restrict__ Pl,           // this wave's [16][40] bf16 scratch
  const bf16x8* qf, int kv, int qb /* wave's first q row (key-index space) */,
  int lane, float* m, float* l, f32x4* cacc)
{
  const int fr = lane & 15, fk = (lane>>4) << 3, rr0 = (lane>>4) << 2;
  f32x4 s[2];
#pragma unroll
  for (int c=0;c<2;++c){
    int kr = kv + c*16 + fr;
    if (MM == 2) kr = (kr < S_LEN) ? kr : (S_LEN-1);
    const u16* kp = Kbase + (size_t)kr * D_K;
    bf16x8 k0 = *(const bf16x8*)(kp + fk);
    bf16x8 k1 = *(const bf16x8*)(kp + 32 + fk);
    f32x4 z = {0.f,0.f,0.f,0.f};
    z = MFMA16(qf[0], k0, z);
    z = MFMA16(qf[1], k1, z);
    s[c] = z;
  }
  float tm[4];
#pragma unroll
  for (int r=0;r<4;++r){
#pragma unroll
    for (int c=0;c<2;++c){
      float v = s[c][r] * 0.125f;                       // 1/sqrt(64)
      if (MM == 1){ if (kv + c*16 + fr > qb + rr0 + r) v = -1e30f; }
      if (MM == 2){ if (!(c == 0 && fr == rr0 + r))    v = -1e30f; }
      s[c][r] = v;
    }
    tm[r] = fmaxf(s[0][r], s[1][r]);
  }
#pragma unroll
  for (int off=1; off<16; off<<=1){
#pragma unroll
    for (int r=0;r<4;++r) tm[r] = fmaxf(tm[r], __shfl_xor(tm[r], off, 64));
  }
  float alpha[4], rs[4];
#pragma unroll
  for (int r=0;r<4;++r){
    const float mn = fmaxf(m[r], tm[r]);
    alpha[r] = __expf(m[r] - mn);
    m[r] = mn;
    const float p0 = __expf(s[0][r] - mn);
    const float p1 = __expf(s[1][r] - mn);
    s[0][r] = p0; s[1][r] = p1;
    rs[r] = p0 + p1;
  }
#pragma unroll
  for (int off=1; off<16; off<<=1){
#pragma unroll
    for (int r=0;r<4;++r) rs[r] += __shfl_xor(rs[r], off, 64);
  }
#pragma unroll
  for (int r=0;r<4;++r) l[r] = l[r]*alpha[r] + rs[r];
#pragma unroll
  for (int d=0; d<4; ++d)
#pragma unroll
    for (int r=0;r<4;++r) cacc[d][r] *= alpha[r];

  // transpose P (C-layout -> A-fragment layout) through wave-local LDS
#pragma unroll
  for (int c=0;c<2;++c)
#pragma unroll
    for (int r=0;r<4;++r)
      Pl[(rr0 + r)*40 + c*16 + fr] = f2bf(s[c][r]);
  asm volatile("s_waitcnt lgkmcnt(0)" ::: "memory");   // wave-local: writes visible
  bf16x8 pf = *(const bf16x8*)&Pl[fr*40 + fk];

#pragma unroll
  for (int d=0; d<4; ++d){
    int vs = kv + fk;
    if (MM == 2) vs = (vs <= S_LEN-8) ? vs : (S_LEN-8);  // clamp; P cols there are 0
    bf16x8 vf = *(const bf16x8*)(Vbase + (size_t)(d*16 + fr)*S_LEN + vs);
    cacc[d] = MFMA16(pf, vf, cacc[d]);
  }
}

// ---------------- prefix causal attention: rows [0,P) ------------------------
__global__ __launch_bounds__(256)
void attn_prefix(const u16* __restrict__ Q, const u16* __restrict__ K,
                 const u16* __restrict__ Vt, u16* __restrict__ ctx)
{
  __shared__ __align__(16) u16 Pl[4][16*40];
  const int bh = blockIdx.x, qt = blockIdx.y;
  const int wid = threadIdx.x >> 6, lane = threadIdx.x & 63;
  const int qb = qt*64 + wid*16;                 // wave's first q row
  const int fr = lane & 15, fk = (lane>>4) << 3, rr0 = (lane>>4) << 2;
  const u16* Kb = K  + (size_t)bh * S_LEN * D_K;
  const u16* Vb = Vt + (size_t)bh * D_K * S_LEN;
  const u16* Qp = Q + ((size_t)bh * S_LEN + qb + fr) * D_K;
  bf16x8 qf[2] = { *(const bf16x8*)(Qp + fk), *(const bf16x8*)(Qp + 32 + fk) };
  float m[4] = {-1e30f,-1e30f,-1e30f,-1e30f};
  float l[4] = {0.f,0.f,0.f,0.f};
  f32x4 cacc[4] = {};

  const int kvend = qb + 16;                     // keys needed: s <= qb+15
  for (int kv = 0; kv < kvend; kv += 32)
    attn_tile<1>(Kb, Vb, Pl[wid], qf, kv, qb, lane, m, l, cacc);

  const int b = bh >> 4, h = bh & 15;
#pragma unroll
  for (int r=0;r<4;++r){
    const float inv = 1.f / l[r];
    const size_t row = (size_t)b*S_LEN + qb + rr0 + r;
#pragma unroll
    for (int d=0; d<4; ++d)
      ctx[row*D_M + h*D_K + d*16 + fr] = f2bf(cacc[d][r] * inv);
  }
}

// ---------------- candidate attention: rows [P,S), keys = prefix + self ------
__global__ __launch_bounds__(256)
void attn_cand(const u16* __restrict__ Q, const u16* __restrict__ K,
               const u16* __restrict__ Vt, u16* __restrict__ ctx)
{
  __shared__ __align__(16) u16 Pl[4][16*40];
  const int bh = blockIdx.x, qt = blockIdx.y;    // qt in [0,4)
  const int wid = threadIdx.x >> 6, lane = threadIdx.x & 63;
  const int ql = qt*64 + wid*16;                 // local candidate row [0,256)
  const int qs = P_LEN + ql;                     // global row in S
  const int fr = lane & 15, fk = (lane>>4) << 3, rr0 = (lane>>4) << 2;
  const u16* Kb = K  + (size_t)bh * S_LEN * D_K;
  const u16* Vb = Vt + (size_t)bh * D_K * S_LEN;
  const u16* Qp = Q + ((size_t)bh * S_LEN + qs + fr) * D_K;
  bf16x8 qf[2] = { *(const bf16x8*)(Qp + fk), *(const bf16x8*)(Qp + 32 + fk) };
  float m[4] = {-1e30f,-1e30f,-1e30f,-1e30f};
  float l[4] = {0.f,0.f,0.f,0.f};
  f32x4 cacc[4] = {};

  for (int kv = 0; kv < P_LEN; kv += 32)         // all prefix keys, no mask
    attn_tile<0>(Kb, Vb, Pl[wid], qf, kv, qs, lane, m, l, cacc);
  attn_tile<2>(Kb, Vb, Pl[wid], qf, P_LEN + ql, qs, lane, m, l, cacc); // self key

  const int b = bh >> 4, h = bh & 15;
#pragma unroll
  for (int r=0;r<4;++r){
    const float inv = 1.f / l[r];
    const size_t row = (size_t)b*S_LEN + qs + rr0 + r;
#pragma unroll
    for (int d=0; d<4; ++d)
      ctx[row*D_M + h*D_K + d*16 + fr] = f2bf(cacc[d][r] * inv);
  }
}

// ---------------- launcher ---------------------------------------------------
extern "C" void kernel_launch(void* const* d_in, const int* in_sizes, int n_in,
                              void* d_out, int out_size, void* d_ws, size_t ws_size,
                              hipStream_t stream)
{
  const float* query = (const float*)d_in[0];
  const float* key   = (const float*)d_in[1];
  const float* value = (const float*)d_in[2];
  const float* Wq = (const float*)d_in[3];
  const float* bq = (const float*)d_in[4];
  const float* Wk = (const float*)d_in[5];
  const float* bk = (const float*)d_in[6];
  const float* Wv = (const float*)d_in[7];
  const float* bv = (const float*)d_in[8];
  const float* Wo = (const float*)d_in[9];
  const float* bo = (const float*)d_in[10];

  if (ws_size < (size_t)(66u<<20)) return;       // fail visibly, don't corrupt

  char* ws = (char*)d_ws;
  u16* Xb = (u16*)(ws);                          // 16 MiB: bf16 input (reused x3), then ctx
  u16* Wb = (u16*)(ws + (16u<<20));              //  2 MiB: bf16 weight (reused x4)
  u16* Qb = (u16*)(ws + (18u<<20));              // 16 MiB: Q (B,H,S,dk)
  u16* Kb = (u16*)(ws + (34u<<20));              // 16 MiB: K (B,H,S,dk)
  u16* Vb = (u16*)(ws + (50u<<20));              // 16 MiB: V^T (B,H,dk,S)
  u16* ctx = Xb;                                 // alias: Xb dead after V GEMM

  const int nX8 = (M_ROWS*D_M)/8, nW8 = (D_M*D_M)/8;
  dim3 gg(M_ROWS/128, D_M/128);                  // (64, 8)

  cvt_bf16<<<2048,256,0,stream>>>(query, Xb, nX8);
  cvt_bf16<<<512, 256,0,stream>>>(Wq,    Wb, nW8);
  gemm_bt<0><<<gg,256,0,stream>>>(Xb, Wb, bq, Qb);

  cvt_bf16<<<2048,256,0,stream>>>(key,   Xb, nX8);
  cvt_bf16<<<512, 256,0,stream>>>(Wk,    Wb, nW8);
  gemm_bt<0><<<gg,256,0,stream>>>(Xb, Wb, bk, Kb);

  cvt_bf16<<<2048,256,0,stream>>>(value, Xb, nX8);
  cvt_bf16<<<512, 256,0,stream>>>(Wv,    Wb, nW8);
  gemm_bt<1><<<gg,256,0,stream>>>(Xb, Wb, bv, Vb);

  attn_prefix<<<dim3(N_H*N_B, P_LEN/64),256,0,stream>>>(Qb, Kb, Vb, ctx);
  attn_cand  <<<dim3(N_H*N_B, (S_LEN-P_LEN)/64),256,0,stream>>>(Qb, Kb, Vb, ctx);

  cvt_bf16<<<512,256,0,stream>>>(Wo, Wb, nW8);
  gemm_bt<2><<<gg,256,0,stream>>>(ctx, Wb, bo, (float*)d_out);
}